// Round 1
// baseline (578.166 us; speedup 1.0000x reference)
//
#include <hip/hip_runtime.h>

#define B_ 8
#define C_ 128
#define L_ 4096
#define P_ 96
#define D_ 16

typedef __attribute__((ext_vector_type(8))) short short8;
typedef __attribute__((ext_vector_type(4))) float float4v;

__device__ __forceinline__ unsigned short f2bf(float f) {
  unsigned int u = __float_as_uint(f);
  u += 0x7fff + ((u >> 16) & 1);          // round-to-nearest-even
  return (unsigned short)(u >> 16);
}

// ---------------------------------------------------------------------------
// Workspace layout (bytes)
// ---------------------------------------------------------------------------
constexpr size_t OFF_H      = 0;                      // h  [B][C][L] f32 : 16 MB
constexpr size_t OFF_PSUM   = 16777216;               // [C][16] f32
constexpr size_t OFF_PSUMSQ = OFF_PSUM + 8192;
constexpr size_t OFF_SCALE  = OFF_PSUMSQ + 8192;      // [C] f32
constexpr size_t OFF_SHIFT  = OFF_SCALE + 512;
constexpr size_t OFF_WALLT  = OFF_SHIFT + 512;        // WallT [c][r] f32 64 KB
constexpr size_t OFF_BALL   = OFF_WALLT + 65536;      // [128] f32
constexpr size_t OFF_QT     = OFF_BALL + 512;         // [B][L][16] bf16 : 1 MB
constexpr size_t OFF_KT     = OFF_QT + 1048576;       // [B][L][16] bf16 : 1 MB
constexpr size_t OFF_V2     = OFF_KT + 1048576;       // [B][96][L] bf16 : 6 MB

// ---------------------------------------------------------------------------
// k_prep: build combined projection weights.
// Rows 0..15 = Wq, 16..31 = Wk, 32..127 = Wv2 = W2 @ Wv (folds final conv in).
// Stored TRANSPOSED: wallT[c*128 + r] so k_proj gets contiguous s_loads.
// ball = {bq, bk, W2 @ bv}. (b2 applied in attention epilogue; bt vanishes
// under BatchNorm shift-invariance and is never read.)
// ---------------------------------------------------------------------------
__global__ __launch_bounds__(128) void k_prep(
    const float* __restrict__ Wq, const float* __restrict__ bq,
    const float* __restrict__ Wk, const float* __restrict__ bk,
    const float* __restrict__ Wv, const float* __restrict__ bv,
    const float* __restrict__ W2,
    float* __restrict__ wallT, float* __restrict__ ball)
{
  const int r = blockIdx.x;
  const int c = threadIdx.x;
  float wv;
  if (r < 16) {
    wv = Wq[r * C_ + c];
  } else if (r < 32) {
    wv = Wk[(r - 16) * C_ + c];
  } else {
    const int p = r - 32;
    float s = 0.f;
    for (int o = 0; o < C_; ++o) s += W2[p * C_ + o] * Wv[o * C_ + c];
    wv = s;
  }
  wallT[c * C_ + r] = wv;
  if (c == 0) {
    float bb;
    if (r < 16)      bb = bq[r];
    else if (r < 32) bb = bk[r - 16];
    else {
      const int p = r - 32;
      float s = 0.f;
      for (int o = 0; o < C_; ++o) s += W2[p * C_ + o] * bv[o];
      bb = s;
    }
    ball[r] = bb;
  }
}

// ---------------------------------------------------------------------------
// k_conv: h[b,o,l] = sum_i x[b,i] * Wt[i,o,l]   (bt skipped — BN cancels it)
// Grid (16 l-tiles, 128 channels), 256 threads. Wt read exactly once (256 MB)
// -> HBM-bound. Deterministic per-block BN partial sums (no atomics).
// ---------------------------------------------------------------------------
__global__ __launch_bounds__(256) void k_conv(
    const float* __restrict__ x, const float* __restrict__ Wt,
    float* __restrict__ h, float* __restrict__ psum, float* __restrict__ psumsq)
{
  __shared__ float4 xs4[256];                 // x as [b][i/4] float4
  __shared__ float rs1[4], rs2[4];
  const int tid = threadIdx.x;
  const int o = blockIdx.y;
  const int l = blockIdx.x * 256 + tid;

  xs4[tid] = ((const float4*)x)[tid];        // 1024 floats exactly
  __syncthreads();

  float acc[8] = {0.f,0.f,0.f,0.f,0.f,0.f,0.f,0.f};
  const float* wp = Wt + (size_t)o * L_ + l;
  const size_t stride = (size_t)C_ * L_;
  for (int i4 = 0; i4 < 32; ++i4) {
    const float w0 = wp[(size_t)(i4 * 4 + 0) * stride];
    const float w1 = wp[(size_t)(i4 * 4 + 1) * stride];
    const float w2 = wp[(size_t)(i4 * 4 + 2) * stride];
    const float w3 = wp[(size_t)(i4 * 4 + 3) * stride];
#pragma unroll
    for (int bb = 0; bb < 8; ++bb) {
      const float4 xb = xs4[bb * 32 + i4];   // same addr across wave: broadcast
      acc[bb] += xb.x * w0;
      acc[bb] += xb.y * w1;
      acc[bb] += xb.z * w2;
      acc[bb] += xb.w * w3;
    }
  }
  float s1 = 0.f, s2 = 0.f;
#pragma unroll
  for (int bb = 0; bb < 8; ++bb) {
    h[((size_t)(bb * C_ + o)) * L_ + l] = acc[bb];
    s1 += acc[bb];
    s2 += acc[bb] * acc[bb];
  }
  for (int off = 1; off < 64; off <<= 1) {
    s1 += __shfl_xor(s1, off);
    s2 += __shfl_xor(s2, off);
  }
  if ((tid & 63) == 0) { rs1[tid >> 6] = s1; rs2[tid >> 6] = s2; }
  __syncthreads();
  if (tid == 0) {
    psum[o * 16 + blockIdx.x]   = rs1[0] + rs1[1] + rs1[2] + rs1[3];
    psumsq[o * 16 + blockIdx.x] = rs2[0] + rs2[1] + rs2[2] + rs2[3];
  }
}

// ---------------------------------------------------------------------------
// k_bn: finalize per-channel scale/shift.  hn = h*scale + shift, then relu.
// ---------------------------------------------------------------------------
__global__ __launch_bounds__(128) void k_bn(
    const float* __restrict__ psum, const float* __restrict__ psumsq,
    const float* __restrict__ gamma, const float* __restrict__ beta,
    float* __restrict__ scale, float* __restrict__ shift)
{
  const int c = threadIdx.x;
  float s1 = 0.f, s2 = 0.f;
  for (int t = 0; t < 16; ++t) { s1 += psum[c * 16 + t]; s2 += psumsq[c * 16 + t]; }
  const float inv = 1.f / 32768.f;
  const float mean = s1 * inv;
  const float var  = s2 * inv - mean * mean;
  const float sc   = rsqrtf(var + 1e-5f) * gamma[c];
  scale[c] = sc;
  shift[c] = beta[c] - mean * sc;
}

// ---------------------------------------------------------------------------
// k_proj: [q;k;v2](r=0..127) = Wall @ relu(bn(h)) + ball, written as bf16.
// Grid (64 l-tiles, 8 b), 256 threads; wave w owns rows [w*32, w*32+32).
// Weights are wave-uniform (readfirstlane) -> s_load + SGPR-operand v_fma.
// Layouts: qT/kT [B][L][16] (A/B-frag friendly), v2 [B][96][L].
// ---------------------------------------------------------------------------
__global__ __launch_bounds__(256) void k_proj(
    const float* __restrict__ h, const float* __restrict__ scale,
    const float* __restrict__ shift, const float* __restrict__ wallT,
    const float* __restrict__ ball,
    unsigned short* __restrict__ qT, unsigned short* __restrict__ kT,
    unsigned short* __restrict__ v2w)
{
  const int b = blockIdx.y;
  const int l0 = blockIdx.x * 64;
  const int tid = threadIdx.x;
  const int wu = __builtin_amdgcn_readfirstlane(tid) >> 6;  // wave id, uniform
  const int lane = tid & 63;
  const int l = l0 + lane;

  float acc[32];
#pragma unroll
  for (int r = 0; r < 32; ++r) acc[r] = ball[wu * 32 + r];

#pragma unroll 2
  for (int c = 0; c < C_; ++c) {
    const float hv = h[((size_t)(b * C_ + c)) * L_ + l];
    const float hn = fmaxf(hv * scale[c] + shift[c], 0.f);
    const float* wrow = wallT + c * C_ + wu * 32;   // 32 consecutive floats
#pragma unroll
    for (int r = 0; r < 32; ++r) acc[r] += wrow[r] * hn;
  }

  if (wu == 0) {
    const size_t row = (size_t)(b * L_ + l) * D_;
    short8 v0, v1;
#pragma unroll
    for (int r = 0; r < 8; ++r) { v0[r] = (short)f2bf(acc[r]); v1[r] = (short)f2bf(acc[8 + r]); }
    *(short8*)(qT + row) = v0;  *(short8*)(qT + row + 8) = v1;
#pragma unroll
    for (int r = 0; r < 8; ++r) { v0[r] = (short)f2bf(acc[16 + r]); v1[r] = (short)f2bf(acc[24 + r]); }
    *(short8*)(kT + row) = v0;  *(short8*)(kT + row + 8) = v1;
  } else {
    const int pbase = wu * 32 - 32;
#pragma unroll
    for (int r = 0; r < 32; ++r)
      v2w[((size_t)(b * P_ + pbase + r)) * L_ + l] = f2bf(acc[r]);
  }
}

// ---------------------------------------------------------------------------
// k_attn: flash attention, bf16 MFMA (16x16x32, d=16 zero-padded to K=32).
// Grid (64 q-tiles of 64 rows, 8 b), 256 threads = 4 waves x 16 q-rows.
// Per m-iter: S = Q K^T (8 MFMA/wave), online softmax, P->LDS (C/D -> A
// layout round trip, wave-private), PV (24 MFMA/wave) vs LDS-staged V.
// y[b,p,l] = O/l_run + b2[p], via LDS transpose for coalesced stores.
// ---------------------------------------------------------------------------
__global__ __launch_bounds__(256, 2) void k_attn(
    const unsigned short* __restrict__ qT, const unsigned short* __restrict__ kT,
    const unsigned short* __restrict__ v2w, const float* __restrict__ b2,
    float* __restrict__ y)
{
  __shared__ __align__(16) char smem[43520];
  unsigned short* ldsV = (unsigned short*)smem;              // [96][136] bf16
  unsigned short* ldsP = (unsigned short*)(smem + 26112);    // [64][136] bf16
  float* ldsO = (float*)smem;                                // [64][100] f32 (epilogue)

  const int b = blockIdx.y;
  const int l0 = blockIdx.x * 64;
  const int tid = threadIdx.x;
  const int w = __builtin_amdgcn_readfirstlane(tid) >> 6;
  const int lane = tid & 63;
  const int quad = lane >> 4;
  const int col = lane & 15;

  // Q fragment: A[m = lane&15][k = quad*8+j], d padded 16->32 with zeros.
  short8 qf = {0,0,0,0,0,0,0,0};
  const int lrow = l0 + w * 16 + col;
  if (quad < 2)
    qf = *(const short8*)(qT + ((size_t)(b * L_ + lrow)) * D_ + quad * 8);

  float4v oacc[6];
#pragma unroll
  for (int i = 0; i < 6; ++i) oacc[i] = (float4v){0.f, 0.f, 0.f, 0.f};
  float mrun[4], lrun[4];
#pragma unroll
  for (int r = 0; r < 4; ++r) { mrun[r] = -1e30f; lrun[r] = 0.f; }

#pragma unroll 1
  for (int mt = 0; mt < L_ / 128; ++mt) {
    const int m0 = mt * 128;
    __syncthreads();   // prior PV reads of ldsV complete before restaging

    // stage V tile [96 p][128 m] -> ldsV[p][m] (pitch 136)
#pragma unroll
    for (int it = 0; it < 6; ++it) {
      const int idx = tid + it * 256;          // 0..1535
      const int p = idx >> 4;
      const int mo = (idx & 15) * 8;
      const short8 vv = *(const short8*)(v2w + ((size_t)(b * P_ + p)) * L_ + m0 + mo);
      *(short8*)(ldsV + p * 136 + mo) = vv;
    }

    // S = Q K^T : B[k=d][n=m] read straight from kT[B][L][16]
    float4v sacc[8];
#pragma unroll
    for (int nt = 0; nt < 8; ++nt) {
      short8 kf = {0,0,0,0,0,0,0,0};
      const int mrow = m0 + nt * 16 + col;
      if (quad < 2)
        kf = *(const short8*)(kT + ((size_t)(b * L_ + mrow)) * D_ + quad * 8);
      sacc[nt] = __builtin_amdgcn_mfma_f32_16x16x32_bf16(
          qf, kf, (float4v){0.f, 0.f, 0.f, 0.f}, 0, 0, 0);
    }

    // online softmax; lane owns rows quad*4+r, cols nt*16+col
    float alpha[4];
#pragma unroll
    for (int r = 0; r < 4; ++r) {
      float mx = sacc[0][r];
#pragma unroll
      for (int nt = 1; nt < 8; ++nt) mx = fmaxf(mx, sacc[nt][r]);
      mx = fmaxf(mx, __shfl_xor(mx, 1));
      mx = fmaxf(mx, __shfl_xor(mx, 2));
      mx = fmaxf(mx, __shfl_xor(mx, 4));
      mx = fmaxf(mx, __shfl_xor(mx, 8));
      const float mnew = fmaxf(mrun[r], mx);
      alpha[r] = __expf(mrun[r] - mnew);
      mrun[r] = mnew;
      float ps = 0.f;
#pragma unroll
      for (int nt = 0; nt < 8; ++nt) {
        const float pv = __expf(sacc[nt][r] - mnew);
        sacc[nt][r] = pv;
        ps += pv;
      }
      ps += __shfl_xor(ps, 1);
      ps += __shfl_xor(ps, 2);
      ps += __shfl_xor(ps, 4);
      ps += __shfl_xor(ps, 8);
      lrun[r] = lrun[r] * alpha[r] + ps;
    }
#pragma unroll
    for (int pt = 0; pt < 6; ++pt)
#pragma unroll
      for (int r = 0; r < 4; ++r) oacc[pt][r] *= alpha[r];

    // P -> LDS (wave-private rows; no barrier needed for P itself)
#pragma unroll
    for (int nt = 0; nt < 8; ++nt)
#pragma unroll
      for (int r = 0; r < 4; ++r)
        ldsP[(w * 16 + quad * 4 + r) * 136 + nt * 16 + col] = f2bf(sacc[nt][r]);

    __syncthreads();   // ldsV staged

    // PV: O[l][p] += P[l][m] V[m][p]
    short8 af[4];
#pragma unroll
    for (int kk = 0; kk < 4; ++kk)
      af[kk] = *(const short8*)(ldsP + (w * 16 + col) * 136 + kk * 32 + quad * 8);
#pragma unroll
    for (int pt = 0; pt < 6; ++pt) {
      float4v o = oacc[pt];
#pragma unroll
      for (int kk = 0; kk < 4; ++kk) {
        const short8 vf = *(const short8*)(ldsV + (pt * 16 + col) * 136 + kk * 32 + quad * 8);
        o = __builtin_amdgcn_mfma_f32_16x16x32_bf16(af[kk], vf, o, 0, 0, 0);
      }
      oacc[pt] = o;
    }
  }

  // epilogue: O/lrun -> LDS transpose -> coalesced y stores (+ b2)
  __syncthreads();
  float inv[4];
#pragma unroll
  for (int r = 0; r < 4; ++r) inv[r] = 1.f / lrun[r];
#pragma unroll
  for (int pt = 0; pt < 6; ++pt)
#pragma unroll
    for (int r = 0; r < 4; ++r)
      ldsO[(w * 16 + quad * 4 + r) * 100 + pt * 16 + col] = oacc[pt][r] * inv[r];
  __syncthreads();
#pragma unroll
  for (int k2 = 0; k2 < 24; ++k2) {
    const int p = w * 24 + k2;
    const float val = ldsO[lane * 100 + p] + b2[p];
    y[((size_t)(b * P_ + p)) * L_ + l0 + lane] = val;
  }
}

// ---------------------------------------------------------------------------
extern "C" void kernel_launch(void* const* d_in, const int* in_sizes, int n_in,
                              void* d_out, int out_size, void* d_ws, size_t ws_size,
                              hipStream_t stream) {
  (void)in_sizes; (void)n_in; (void)out_size; (void)ws_size;
  const float* x     = (const float*)d_in[0];
  const float* Wt    = (const float*)d_in[1];
  // d_in[2] = bt: unused — BatchNorm mean-subtraction cancels it exactly.
  const float* gamma = (const float*)d_in[3];
  const float* beta  = (const float*)d_in[4];
  const float* Wq    = (const float*)d_in[5];
  const float* bq    = (const float*)d_in[6];
  const float* Wk    = (const float*)d_in[7];
  const float* bk    = (const float*)d_in[8];
  const float* Wv    = (const float*)d_in[9];
  const float* bv    = (const float*)d_in[10];
  const float* W2    = (const float*)d_in[11];
  const float* b2    = (const float*)d_in[12];
  float* y = (float*)d_out;

  char* ws = (char*)d_ws;
  float* h       = (float*)(ws + OFF_H);
  float* psum    = (float*)(ws + OFF_PSUM);
  float* psumsq  = (float*)(ws + OFF_PSUMSQ);
  float* scale   = (float*)(ws + OFF_SCALE);
  float* shift   = (float*)(ws + OFF_SHIFT);
  float* wallT   = (float*)(ws + OFF_WALLT);
  float* ball    = (float*)(ws + OFF_BALL);
  unsigned short* qT  = (unsigned short*)(ws + OFF_QT);
  unsigned short* kT  = (unsigned short*)(ws + OFF_KT);
  unsigned short* v2w = (unsigned short*)(ws + OFF_V2);

  k_prep<<<128, 128, 0, stream>>>(Wq, bq, Wk, bk, Wv, bv, W2, wallT, ball);
  k_conv<<<dim3(16, 128), 256, 0, stream>>>(x, Wt, h, psum, psumsq);
  k_bn<<<1, 128, 0, stream>>>(psum, psumsq, gamma, beta, scale, shift);
  k_proj<<<dim3(64, 8), 256, 0, stream>>>(h, scale, shift, wallT, ball, qT, kT, v2w);
  k_attn<<<dim3(64, 8), 256, 0, stream>>>(qT, kT, v2w, b2, y);
}